// Round 7
// baseline (810.488 us; speedup 1.0000x reference)
//
#include <hip/hip_runtime.h>

// SelfAttention: x(8,2048,768) fp32, W_q/W_k/W_v (768,768) fp32 -> H fp32.
// Algebraic rewrite: S = x (Wq^T Wk / sqrt(D)) x^T:
//   prep: cvt(x,Wv) + transpose(Wq,Wk)  [one launch]
//   G2 = NT(WkT,WqT)*scale ; {T~ = NT(x,G2), Vt = (x@Wv^T)^T} [one launch, z-switch]
//   P' = exp(NT(T~,x)) + rowsum partials ; H = NT(P',Vt)/rowsum
// GEMM core (new): B-operand staged via global_load_lds(16B) + swizzled LDS;
// A-fragments loaded DIRECTLY global->VGPR (16B contiguous per lane, wave
// covers full 64B lines) — halves LDS traffic (96->48 KB/block-iter), which
// the R3/R6 counters show is the binding pipe (MfmaUtil ceiling ~26%).

typedef _Float16 f16;
typedef __attribute__((ext_vector_type(4))) _Float16 f16x4;
typedef __attribute__((ext_vector_type(8))) _Float16 f16x8;
typedef __attribute__((ext_vector_type(4))) float    f32x4;

#define BM 128
#define BN 128
#define BKH 64                      // K-tile in halfs (128 B rows)

#define SEQ   2048
#define DIM   768
#define NBAT  8
#define MTOT  (NBAT * SEQ)          // 16384
#define XN    ((long)MTOT * DIM)    // 12582912
#define WN    (DIM * DIM)           // 589824
#define SB    ((long)SEQ * SEQ)
#define QB    ((long)SEQ * DIM)
#define XN4   3145728               // XN/4
#define WN4   147456                // WN/4
#define CVT_BLOCKS 12864            // (XN4+WN4)/256

__device__ __forceinline__ void async_cp16(const void* g, void* l) {
  __builtin_amdgcn_global_load_lds((__attribute__((address_space(1))) void*)g,
                                   (__attribute__((address_space(3))) void*)l,
                                   16, 0, 0);
}

// One launch: fp32->f16 cvt of x and Wv, plus transposed cvt of Wq,Wk.
__global__ void prep(const float* __restrict__ x, const float* __restrict__ wv,
                     const float* __restrict__ wq, const float* __restrict__ wk,
                     f16* __restrict__ x16, f16* __restrict__ wv16,
                     f16* __restrict__ wqt, f16* __restrict__ wkt) {
  __shared__ float t[32][33];
  const int b = blockIdx.x;
  if (b < CVT_BLOCKS) {
    int i = b * 256 + threadIdx.x;      // float4 index
    const float* src; f16* dst; int idx;
    if (i < XN4) { src = x; dst = x16; idx = i; }
    else { src = wv; dst = wv16; idx = i - XN4; }
    float4 v = ((const float4*)src)[idx];
    f16x4 o = {(f16)v.x, (f16)v.y, (f16)v.z, (f16)v.w};
    ((f16x4*)dst)[idx] = o;
  } else {
    int b2 = b - CVT_BLOCKS;            // 0..1151
    int zz = b2 >= 576;
    int r  = zz ? b2 - 576 : b2;
    const float* src = zz ? wk : wq;
    f16* dst = zz ? wkt : wqt;
    const int bx = (r % 24) * 32, by = (r / 24) * 32;
    const int tx = threadIdx.x & 31, ty = threadIdx.x >> 5;   // 32 x 8
#pragma unroll
    for (int rr = 0; rr < 4; ++rr)
      t[ty + 8 * rr][tx] = src[(long)(by + ty + 8 * rr) * DIM + bx + tx];
    __syncthreads();
#pragma unroll
    for (int rr = 0; rr < 4; ++rr)
      dst[(long)(bx + ty + 8 * rr) * DIM + by + tx] = (f16)t[tx][ty + 8 * rr];
  }
}

// NT GEMM: C[m][n] = sum_k A[m][k]*B[n][k].  128x128 block, 4 waves of 64x64.
// B staged to LDS (swizzled, DMA); A-fragments direct global->VGPR.
// MODE 0: f16 row-major out; z==0 scaled by `scale` (G2).
// MODE 1: f16 out = exp(acc); rowsum partials -> Rsum[z][32][2048].
// MODE 2: fp32 out = acc * (1/rowsum) from Rsum partials.
// MODE 4: merged projection: z==0 -> T~ row-major f16; z==1 -> Vt transposed.
// swap(mfma(bf,af)): lane&15 = m, regs = 4 consecutive n.
// noswap(mfma(af,bf)): lane&15 = n, regs = 4 consecutive m (transposed out).
template <int MODE>
__global__ __launch_bounds__(256, 4)
void gemm_nt(const f16* __restrict__ Abase, long sAz,
             const f16* __restrict__ Bbase, long sBz,
             void* __restrict__ Cbase, long sCz,
             float* __restrict__ Rsum,
             int N, int K, float scale)
{
  __shared__ __align__(16) char smem[34816];   // lB 16 KB in-loop; epilogue aliases
  __shared__ float sinv[128];                  // MODE2 per-row 1/rowsum
  f16* lB = (f16*)smem;                        // [128][64] halfs

  const int tid  = threadIdx.x;
  const int z    = blockIdx.z;
  const int m0   = blockIdx.x * BM;
  const int n0   = blockIdx.y * BN;
  const int wave = tid >> 6;
  const int lane = tid & 63;
  const int wm   = (wave & 1) * 64;
  const int wn   = (wave >> 1) * 64;

  const bool swp = (MODE != 4) || (z == 0);    // mfma operand order

  const f16* A = Abase + (long)z * sAz;
  const f16* B = Bbase + (long)z * sBz;

  f32x4 acc[4][4] = {};

  if constexpr (MODE == 2) {
    if (tid < 128) {
      const float* rp = Rsum + (long)z * 32 * SEQ + m0 + tid;
      float s = 0.f;
#pragma unroll
      for (int k = 0; k < 32; ++k) s += rp[k * SEQ];
      sinv[tid] = 1.0f / s;
    }
    // ordered before epilogue reads by the in-loop barriers
  }

  // B staging: thread t loads 16B: row srow (of 32-row group p), swizzled chunk.
  const int srow = tid >> 3;                         // 0..31
  const int gcol = ((tid & 7) ^ (srow & 7)) * 8;     // swizzle chunk by row&7
  const f16* gb = B + (long)(n0 + srow) * K + gcol;
  f16* lb = lB + tid * 8;

  // Fragment addressing
  const int frow = lane & 15;
  const int q    = lane >> 4;
  const int swz  = frow & 7;
  const int bro  = (wn + frow) * BKH;
  // A direct: row = m0 + wm + i*16 + frow; k = k0 + s*32 + q*8 (16B contiguous)
  const f16* ap0 = A + (long)(m0 + wm + frow) * K + q * 8;

  for (int k0 = 0; k0 < K; k0 += BKH) {
#pragma unroll
    for (int p = 0; p < 4; ++p)
      async_cp16(gb + (long)(p * 32) * K + k0, lb + p * 2048);
    __syncthreads();
    // hoist all A-loads for both phases (latency overlap with LDS reads/MFMA)
    f16x8 af[2][4];
#pragma unroll
    for (int i = 0; i < 4; ++i) {
      const f16* a = ap0 + (long)(i * 16) * K + k0;
      af[0][i] = *(const f16x8*)a;
      af[1][i] = *(const f16x8*)(a + 32);
    }
#pragma unroll
    for (int s = 0; s < 2; ++s) {
      const int co = ((s * 4 + q) ^ swz) * 8;
      f16x8 bf[4];
#pragma unroll
      for (int j = 0; j < 4; ++j) bf[j] = *(const f16x8*)&lB[bro + j * 1024 + co];
      if (swp) {
#pragma unroll
        for (int i = 0; i < 4; ++i)
#pragma unroll
          for (int j = 0; j < 4; ++j)
            acc[i][j] = __builtin_amdgcn_mfma_f32_16x16x32_f16(bf[j], af[s][i], acc[i][j], 0, 0, 0);
      } else {
#pragma unroll
        for (int i = 0; i < 4; ++i)
#pragma unroll
          for (int j = 0; j < 4; ++j)
            acc[i][j] = __builtin_amdgcn_mfma_f32_16x16x32_f16(af[s][i], bf[j], acc[i][j], 0, 0, 0);
      }
    }
    __syncthreads();   // bf reads done before next stage overwrites
  }

  const int TS = 136;  // f16 epilogue tile stride (halfs)

  if constexpr (MODE == 0 || MODE == 1) {
    f16* T = (f16*)smem;   // [128][TS]
    float rs[4] = {0.f, 0.f, 0.f, 0.f};
    const float sc = (MODE == 0 && z == 0) ? scale : 1.0f;
#pragma unroll
    for (int i = 0; i < 4; ++i)
#pragma unroll
      for (int j = 0; j < 4; ++j) {
        f16x4 v;
#pragma unroll
        for (int r = 0; r < 4; ++r) {
          float xv = acc[i][j][r];
          if (MODE == 1) xv = __expf(xv); else xv *= sc;
          v[r] = (f16)xv;
          if (MODE == 1) rs[i] += (float)v[r];   // sum of f16-rounded values
        }
        *(f16x4*)&T[(wm + i * 16 + frow) * TS + wn + j * 16 + q * 4] = v;
      }
    if constexpr (MODE == 1) {
#pragma unroll
      for (int i = 0; i < 4; ++i) {
        rs[i] += __shfl_xor(rs[i], 16);
        rs[i] += __shfl_xor(rs[i], 32);   // full 64-col segment sum
      }
      if (lane < 16) {   // q==0 lanes hold the reduced sums
        float* rp = Rsum + ((long)z * 32 + blockIdx.y * 2 + (wn >> 6)) * SEQ + m0 + wm;
#pragma unroll
        for (int i = 0; i < 4; ++i) rp[i * 16 + frow] = rs[i];
      }
    }
    __syncthreads();
    f16* C = (f16*)Cbase + (long)z * sCz;
    const int row = tid >> 1, seg = (tid & 1) * 64;
#pragma unroll
    for (int k = 0; k < 8; ++k) {
      f16x8 v = *(const f16x8*)&T[row * TS + seg + k * 8];
      *(f16x8*)&C[(long)(m0 + row) * N + n0 + seg + k * 8] = v;
    }
  }

  if constexpr (MODE == 4) {
    if (z == 0) {          // T~ row-major f16 (no scale; G2 carries it)
      f16* T = (f16*)smem;
#pragma unroll
      for (int i = 0; i < 4; ++i)
#pragma unroll
        for (int j = 0; j < 4; ++j) {
          f16x4 v = {(f16)acc[i][j][0], (f16)acc[i][j][1],
                     (f16)acc[i][j][2], (f16)acc[i][j][3]};
          *(f16x4*)&T[(wm + i * 16 + frow) * TS + wn + j * 16 + q * 4] = v;
        }
      __syncthreads();
      f16* C = (f16*)Cbase;
      const int row = tid >> 1, seg = (tid & 1) * 64;
#pragma unroll
      for (int k = 0; k < 8; ++k) {
        f16x8 v = *(const f16x8*)&T[row * TS + seg + k * 8];
        *(f16x8*)&C[(long)(m0 + row) * N + n0 + seg + k * 8] = v;
      }
    } else {               // Vt[b][d][s]; noswap: regs = consecutive m (=s)
      f16* T = (f16*)smem; // [n(=d) 128][TS] holding m(=s) contiguous
#pragma unroll
      for (int i = 0; i < 4; ++i)
#pragma unroll
        for (int j = 0; j < 4; ++j) {
          f16x4 v = {(f16)acc[i][j][0], (f16)acc[i][j][1],
                     (f16)acc[i][j][2], (f16)acc[i][j][3]};
          *(f16x4*)&T[(wn + j * 16 + frow) * TS + wm + i * 16 + q * 4] = v;
        }
      __syncthreads();
      f16* C = (f16*)Cbase + sCz;
      const int b = m0 >> 11, sl = m0 & 2047;
      const int row = tid >> 1, seg = (tid & 1) * 64;
#pragma unroll
      for (int k = 0; k < 8; ++k) {
        f16x8 v = *(const f16x8*)&T[row * TS + seg + k * 8];
        *(f16x8*)&C[(long)b * QB + (long)(n0 + row) * SEQ + sl + seg + k * 8] = v;
      }
    }
  }

  if constexpr (MODE == 2) {   // fp32 out, normalized; 2-pass (64 rows) epilogue
    float inv[4];
#pragma unroll
    for (int i = 0; i < 4; ++i) inv[i] = sinv[wm + i * 16 + frow];

    float* Tf = (float*)smem;   // [64][FS] fp32
    const int FS = 132;
    float* C = (float*)Cbase + (long)z * sCz;
    for (int pass = 0; pass < 2; ++pass) {
      if (wm == pass * 64) {
#pragma unroll
        for (int i = 0; i < 4; ++i)
#pragma unroll
          for (int j = 0; j < 4; ++j) {
            f32x4 v = acc[i][j] * inv[i];
            *(f32x4*)&Tf[(i * 16 + frow) * FS + wn + j * 16 + q * 4] = v;
          }
      }
      __syncthreads();
      const int row = tid >> 2, cs = (tid & 3) * 32;
#pragma unroll
      for (int k = 0; k < 8; ++k) {
        f32x4 v = *(const f32x4*)&Tf[row * FS + cs + k * 4];
        *(f32x4*)&C[(long)(m0 + pass * 64 + row) * N + n0 + cs + k * 4] = v;
      }
      if (pass == 0) __syncthreads();
    }
  }
}

extern "C" void kernel_launch(void* const* d_in, const int* in_sizes, int n_in,
                              void* d_out, int out_size, void* d_ws, size_t ws_size,
                              hipStream_t stream) {
  const float* x  = (const float*)d_in[0];
  const float* Wq = (const float*)d_in[1];
  const float* Wk = (const float*)d_in[2];
  const float* Wv = (const float*)d_in[3];

  f16* ws    = (f16*)d_ws;
  f16* x16   = ws;                  // XN
  f16* Wv16  = x16 + XN;            // WN
  f16* WqT16 = Wv16 + WN;           // WN
  f16* WkT16 = WqT16 + WN;          // WN
  f16* G2    = WkT16 + WN;          // WN   G2[e][d] = sum_k Wk[k][e]Wq[k][d]*scale
  f16* T16   = G2 + WN;             // XN   T~ = x @ G2^T
  f16* Vt16  = T16 + XN;            // XN   [b][d][s]
  f16* S16   = Vt16 + XN;           // NBAT*SB (exp scores, unnormalized)
  float* rsumP = (float*)(S16 + (long)NBAT * SB);   // [8][32][2048] partials

  // 1. cvt + weight transposes (one launch)
  prep<<<CVT_BLOCKS + 1152, 256, 0, stream>>>(x, Wv, Wq, Wk, x16, Wv16, WqT16, WkT16);

  dim3 blk(256);
  // 2. G2 = NT(WkT, WqT) * 1/sqrt(768)  (768x768x768)
  gemm_nt<0><<<dim3(6, 6, 1), blk, 0, stream>>>(
      WkT16, 0L, WqT16, 0L, (void*)G2, 0L, nullptr, DIM, DIM, 0.03608439182435161f);
  // 3. merged: z=0 T~ = NT(x,G2); z=1 Vt = (x@Wv^T)^T   (16384x768x768 each)
  gemm_nt<4><<<dim3(MTOT / BM, DIM / BN, 2), blk, 0, stream>>>(
      x16, 0L, G2, (long)(Wv16 - G2), (void*)T16, (long)(Vt16 - T16), nullptr,
      DIM, DIM, 1.0f);
  // 4. P' = exp(T~ x^T) per batch + rowsum partials  (2048x2048x768 x8)
  gemm_nt<1><<<dim3(SEQ / BM, SEQ / BN, NBAT), blk, 0, stream>>>(
      T16, QB, x16, QB, (void*)S16, SB, rsumP, SEQ, DIM, 1.0f);
  // 5. H = (P' @ Vt^T) / rowsum, fp32  (2048x768x2048 x8)
  gemm_nt<2><<<dim3(SEQ / BM, DIM / BN, NBAT), blk, 0, stream>>>(
      S16, SB, Vt16, QB, d_out, QB, rsumP, DIM, SEQ, 1.0f);
}